// Round 11
// baseline (389.346 us; speedup 1.0000x reference)
//
#include <hip/hip_runtime.h>

// Batched 16-qubit statevector sim. One 1024-thread block per batch element.
// State idx bits: [5:0] = register (64 f32/thread), [11:6] = lane, [15:12] = wave.
// Qubit q <-> idx bit (15-q). CNOT staircase via GF(2) relabeling (tables =
// rows/cols of powers of staircase matrix T); only CNOT(12,11) and CNOT(6,5)
// move data. Tables hand-verified r1; correctness measured (passed r2/r4/r10).
//
// Measured history: R2 baseline 350us, VGPR_Count=64 -> st[64] spills to
// scratch (~720 MB/dispatch HBM, VALUBusy 25%). R4: __launch_bounds__(1024,4)
// no-op (still 64). R10: amdgpu_waves_per_eu(4,4) ALSO no-op (still 64).
// The backend's VGPR hard cap stayed at pool(512)/8waves = 64 despite both.
//
// R11: attribute probe. Same verified body under 4 attribute combos; host
// dispatch picks the variant with least scratch (localSizeBytes) via
// hipFuncGetAttributes (capture-safe, deterministic). Worst case = current
// behavior. Decision gate: any variant >64 VGPR -> spill fixed; all 64 ->
// plan B (32 regs resident + 32 parked in LDS) next round.

__device__ __constant__ unsigned char WM[4][4] = {
  {0x1,0x2,0x4,0x8},{0x1,0x3,0x6,0xC},{0x1,0x2,0x5,0xA},{0x1,0x3,0x7,0xF}};
__device__ __constant__ unsigned char WS[4][4] = {
  {0x1,0x2,0x4,0x8},{0xF,0xE,0xC,0x8},{0x5,0xA,0x4,0x8},{0x3,0x6,0xC,0x8}};
__device__ __constant__ unsigned char LM[4][6] = {
  {0x01,0x02,0x04,0x08,0x10,0x20},
  {0x01,0x03,0x06,0x0C,0x18,0x30},
  {0x01,0x02,0x05,0x0A,0x14,0x28},
  {0x01,0x03,0x07,0x0F,0x1E,0x3C}};
__device__ __constant__ unsigned char LS[4][6] = {
  {0x01,0x02,0x04,0x08,0x10,0x20},
  {0x3F,0x3E,0x3C,0x38,0x30,0x20},
  {0x15,0x2A,0x14,0x28,0x10,0x20},
  {0x33,0x26,0x0C,0x18,0x30,0x20}};
__device__ __constant__ unsigned char WC[4]   = {0xF,0x5,0x3,0x1};
__device__ __constant__ unsigned char TM11[4] = {0x20,0x30,0x28,0x3C};
__device__ __constant__ unsigned char LC[4]   = {0x3F,0x15,0x33,0x11};

__device__ __forceinline__ void qsim_body(const float* __restrict__ x,
                                          const float* __restrict__ wts,
                                          float* __restrict__ out) {
  __shared__ float2 xbuf[16][16][64];   // [wave][float2-slot][lane]
  __shared__ float2 ang[80];            // [0..15]: x RYs; [16+16l+q]: layer l

  const int tid   = threadIdx.x;
  const int lane  = tid & 63;
  const int wv    = tid >> 6;
  const int batch = blockIdx.x;

  if (tid < 80) {
    float th = (tid < 16) ? x[batch * 16 + tid] : wts[tid - 16];
    float s, c;
    sincosf(0.5f * th, &s, &c);
    ang[tid] = make_float2(c, s);
  }
  __syncthreads();

  float st[64];

  // ---- init: product state ----
  {
    float f = 1.0f;
#pragma unroll
    for (int b = 0; b < 4; ++b) { float2 a = ang[3 - b]; f *= ((wv   >> b) & 1) ? a.y : a.x; }
#pragma unroll
    for (int e = 0; e < 6; ++e) { float2 a = ang[9 - e]; f *= ((lane >> e) & 1) ? a.y : a.x; }
    st[0] = f;
#pragma unroll
    for (int k = 0; k < 6; ++k) {
      float2 a = ang[15 - k];
      const int m = 1 << k;
#pragma unroll
      for (int r = 0; r < (1 << k); ++r) {
        st[r + m] = st[r] * a.y;
        st[r]     = st[r] * a.x;
      }
    }
  }

  for (int l = 0; l < 4; ++l) {
    const float2* la = &ang[16 + l * 16];

    // ---- RY on reg bits ----
#pragma unroll
    for (int k = 0; k < 6; ++k) {
      const float2 a = la[15 - k];
      const int m = 1 << k;
#pragma unroll
      for (int r = 0; r < 64; ++r) {
        if (!(r & m)) {
          float s0 = st[r], s1 = st[r + m];
          st[r]     = a.x * s0 - a.y * s1;
          st[r + m] = a.y * s0 + a.x * s1;
        }
      }
    }

    // ---- RY on lane bits: shfl_xor ----
    for (int e = 0; e < 6; ++e) {
      const float2 a = la[9 - e];
      const int m = LM[l][e];
      const float sg = (__popc(lane & LS[l][e]) & 1) ? a.y : -a.y;
#pragma unroll
      for (int r = 0; r < 64; ++r) {
        float o = __shfl_xor(st[r], m);
        st[r] = fmaf(sg, o, a.x * st[r]);
      }
    }

    // ---- RY on wave bits: LDS exchange, 2 chunks ----
    for (int b = 0; b < 4; ++b) {
      const float2 a = la[3 - b];
      const int pw = wv ^ WM[l][b];
      const float sg = (__popc(wv & WS[l][b]) & 1) ? a.y : -a.y;
#pragma unroll
      for (int ch = 0; ch < 2; ++ch) {
        const int base = ch * 32;
        __syncthreads();
#pragma unroll
        for (int k2 = 0; k2 < 16; ++k2)
          xbuf[wv][k2][lane] = make_float2(st[base + 2*k2], st[base + 2*k2 + 1]);
        __syncthreads();
#pragma unroll
        for (int k2 = 0; k2 < 16; ++k2) {
          float2 o = xbuf[pw][k2][lane];
          st[base + 2*k2]     = fmaf(sg, o.x, a.x * st[base + 2*k2]);
          st[base + 2*k2 + 1] = fmaf(sg, o.y, a.x * st[base + 2*k2 + 1]);
        }
      }
    }

    // ---- CNOT staircase ----
    {
      const int tm = TM11[l];
      if (__popc(wv & WC[l]) & 1) {
#pragma unroll
        for (int r = 0; r < 64; ++r) st[r] = __shfl_xor(st[r], tm);
      }
    }
    {
      const bool cl = (__popc(lane & LC[l]) & 1) != 0;
#pragma unroll
      for (int r = 0; r < 32; ++r) {
        float u = st[r], v = st[r + 32];
        st[r]      = cl ? v : u;
        st[r + 32] = cl ? u : v;
      }
    }
#pragma unroll
    for (int pc = 5; pc >= 1; --pc) {
      const int cm = 1 << pc, tm2 = 1 << (pc - 1);
#pragma unroll
      for (int r = 0; r < 64; ++r) {
        if ((r & cm) && !(r & tm2)) {
          float t = st[r]; st[r] = st[r + tm2]; st[r + tm2] = t;
        }
      }
    }
  }

  if (tid == 0) {
#pragma unroll
    for (int j = 0; j < 16; ++j) out[batch * 16 + j] = st[j];
  }
}

// Variant 0: num_vgpr + waves_per_eu
__global__ __launch_bounds__(1024)
__attribute__((amdgpu_num_vgpr(128), amdgpu_waves_per_eu(4, 4)))
void qsim_nv_wpe(const float* x, const float* w, float* o) { qsim_body(x, w, o); }

// Variant 1: num_vgpr only
__global__ __launch_bounds__(1024)
__attribute__((amdgpu_num_vgpr(128)))
void qsim_nv(const float* x, const float* w, float* o) { qsim_body(x, w, o); }

// Variant 2: explicit flat_work_group_size (no HIP launch_bounds macro) + waves_per_eu
__global__
__attribute__((amdgpu_flat_work_group_size(1024, 1024), amdgpu_waves_per_eu(4, 4)))
void qsim_fw(const float* x, const float* w, float* o) { qsim_body(x, w, o); }

// Variant 3: r10 baseline (known-measured fallback)
__global__ __launch_bounds__(1024)
__attribute__((amdgpu_waves_per_eu(4, 4)))
void qsim_wpe(const float* x, const float* w, float* o) { qsim_body(x, w, o); }

extern "C" void kernel_launch(void* const* d_in, const int* in_sizes, int n_in,
                              void* d_out, int out_size, void* d_ws, size_t ws_size,
                              hipStream_t stream) {
  const float* x   = (const float*)d_in[0];
  const float* wts = (const float*)d_in[1];
  float* out = (float*)d_out;
  const int batch = in_sizes[0] / 16;   // 512

  // Pick the variant with the least scratch (spill), then most registers.
  // hipFuncGetAttributes is a host-side query: graph-capture-safe and
  // deterministic (same choice every call).
  typedef void (*KFn)(const float*, const float*, float*);
  KFn ks[4] = {qsim_nv_wpe, qsim_nv, qsim_fw, qsim_wpe};
  int best = 3;                      // default: known-measured fallback
  size_t bestLocal = (size_t)-1;
  int bestRegs = -1;
  for (int i = 0; i < 4; ++i) {
    hipFuncAttributes a;
    if (hipFuncGetAttributes(&a, (const void*)ks[i]) != hipSuccess) continue;
    if (a.localSizeBytes < bestLocal ||
        (a.localSizeBytes == bestLocal && a.numRegs > bestRegs)) {
      bestLocal = a.localSizeBytes;
      bestRegs  = a.numRegs;
      best = i;
    }
  }
  ks[best]<<<dim3(batch), dim3(1024), 0, stream>>>(x, wts, out);
}

// Round 12
// 303.409 us; speedup vs baseline: 1.2832x; 1.2832x over previous
//
#include <hip/hip_runtime.h>

// Batched 16-qubit statevector sim, 64-VGPR-budget edition.
// One 1024-thread block per batch element. Amp bits: [15:12]=wave, [11:6]=lane,
// [5]=SPLIT (reg half vs LDS half), [4:0]=slot. Qubit q <-> amp bit (15-q).
//
// Measured history: R2/R4/R10/R11: compiler hard-caps VGPR at 64 (pool 512 /
// 8 waves target); st[64] spilled -> ~720 MB scratch HBM traffic/dispatch,
// ~350 us, VALUBusy 25%. launch_bounds(1024,4), waves_per_eu(4,4),
// num_vgpr(128), flat_work_group_size all failed to lift the cap (R11 probe).
// => R12: restructure to fit 64 VGPRs: 32 amps in registers (bit5=0) +
// 32 amps in LDS (bit5=1), L[16][64][34] f32 (pad 34: 2-way bank alias, free).
//
// Gates:
//  - reg-bit RYs b0..b4 + split-bit RY b5: chunked LDS<->reg, pure VALU.
//  - lane-bit RYs: shfl_xor on reg half; partner-lane LDS RMW on LDS half
//    (same-wave LDS ops are program-ordered -> race-free, no barrier).
//  - wave-bit RYs: one-sided pair update on LDS half (handler wave w computes
//    BOTH sides of pair (w, w^m) on its slot range: lower->slots 0..15,
//    upper->16..31; disjoint writes, 1 barrier/gate); both halves covered via
//    swap st<->L between two rounds (10 barriers/layer).
//  - CNOT staircase: wave/lane relabels via r1-verified tables (WM/WS/LM/LS/
//    WC/TM11/LC verbatim). Reg cascade (b5->b4)..(b1->b0) composite is
//    s' = T5(s) ^ (31*bit5), T5 = suffix-xor map; folded for FREE into SWAP2
//    via constexpr perms AQ (LDS side) + CHI (register rename): CHI∘AQ = T5,
//    storage_final[q] = st_old[AQ[q]] realizes L-half map T5^31.
//    (6,5) boundary conjugated by the fold: ctrl lanes do st[k]<->L[k^31].
//  - (12,11): ctrl waves: shfl_xor(tm) on reg half + partner-lane LDS copy.

__device__ __constant__ unsigned char WM[4][4] = {
  {0x1,0x2,0x4,0x8},{0x1,0x3,0x6,0xC},{0x1,0x2,0x5,0xA},{0x1,0x3,0x7,0xF}};
__device__ __constant__ unsigned char WS[4][4] = {
  {0x1,0x2,0x4,0x8},{0xF,0xE,0xC,0x8},{0x5,0xA,0x4,0x8},{0x3,0x6,0xC,0x8}};
__device__ __constant__ unsigned char LM[4][6] = {
  {0x01,0x02,0x04,0x08,0x10,0x20},
  {0x01,0x03,0x06,0x0C,0x18,0x30},
  {0x01,0x02,0x05,0x0A,0x14,0x28},
  {0x01,0x03,0x07,0x0F,0x1E,0x3C}};
__device__ __constant__ unsigned char LS[4][6] = {
  {0x01,0x02,0x04,0x08,0x10,0x20},
  {0x3F,0x3E,0x3C,0x38,0x30,0x20},
  {0x15,0x2A,0x14,0x28,0x10,0x20},
  {0x33,0x26,0x0C,0x18,0x30,0x20}};
__device__ __constant__ unsigned char WC[4]   = {0xF,0x5,0x3,0x1};
__device__ __constant__ unsigned char TM11[4] = {0x20,0x30,0x28,0x3C};
__device__ __constant__ unsigned char LC[4]   = {0x3F,0x15,0x33,0x11};

// AQ[q] = gray(q^31): SWAP2 pairing; CHI[i] = T5^2(i)^21: register rename.
// (constexpr C++ arrays -> compile-time indices after unroll; NOT __constant__,
//  which would force runtime register indexing -> scratch.)
static constexpr int AQ[32] = {
  16,17,19,18,22,23,21,20,28,29,31,30,26,27,25,24,
   8, 9,11,10,14,15,13,12, 4, 5, 7, 6, 2, 3, 1, 0};
static constexpr int CHI[32] = {
  21,20,23,22,16,17,18,19,31,30,29,28,26,27,24,25,
   0, 1, 2, 3, 5, 4, 7, 6,10,11, 8, 9,15,14,13,12};

__global__ __launch_bounds__(1024)
void qsim_kernel(const float* __restrict__ x, const float* __restrict__ wts,
                 float* __restrict__ out) {
  __shared__ float  Lbuf[16][64][34];   // 139264 B; pad 34 -> 2-way banks (free)
  __shared__ float2 ang[80];            // [0..15]: x RYs; [16+16l+q]: layer l

  const int tid   = threadIdx.x;
  const int lane  = tid & 63;
  const int wv    = tid >> 6;
  const int batch = blockIdx.x;

  if (tid < 80) {
    float th = (tid < 16) ? x[batch * 16 + tid] : wts[tid - 16];
    float s, c;
    sincosf(0.5f * th, &s, &c);
    ang[tid] = make_float2(c, s);
  }
  __syncthreads();

  float st[32];
  float2* Lf2 = (float2*)&Lbuf[wv][lane][0];

  // ---- init: product state; reg half gets c(q10), LDS half s(q10) ----
  {
    float f = 1.0f;
#pragma unroll
    for (int b = 0; b < 4; ++b) { float2 a = ang[3 - b]; f *= ((wv   >> b) & 1) ? a.y : a.x; }
#pragma unroll
    for (int e = 0; e < 6; ++e) { float2 a = ang[9 - e]; f *= ((lane >> e) & 1) ? a.y : a.x; }
    st[0] = f;
#pragma unroll
    for (int k = 0; k < 5; ++k) {
      float2 a = ang[15 - k];
      const int m = 1 << k;
#pragma unroll
      for (int r = 0; r < 16; ++r) if (r < m) {
        st[r + m] = st[r] * a.y;
        st[r]     = st[r] * a.x;
      }
    }
    float2 a10 = ang[10];
#pragma unroll
    for (int p = 0; p < 16; ++p) {
      Lf2[p] = make_float2(st[2*p] * a10.y, st[2*p+1] * a10.y);
      st[2*p] *= a10.x; st[2*p+1] *= a10.x;
    }
  }

  for (int l = 0; l < 4; ++l) {
    const float2* la = &ang[16 + l * 16];

    // ---- P1: reg-bit RYs b0..b3 (two 16-amp chunks) + b5, then b4 ----
#pragma unroll
    for (int c = 0; c < 2; ++c) {
      float t[16];
#pragma unroll
      for (int p = 0; p < 8; ++p) { float2 v = Lf2[8*c + p]; t[2*p] = v.x; t[2*p+1] = v.y; }
#pragma unroll
      for (int k = 0; k < 4; ++k) {
        const float2 a = la[15 - k];
        const int m = 1 << k;
#pragma unroll
        for (int r = 0; r < 16; ++r) if (!(r & m)) {
          float u0 = t[r], u1 = t[r + m];
          t[r]     = a.x*u0 - a.y*u1;
          t[r + m] = a.y*u0 + a.x*u1;
          float v0 = st[16*c + r], v1 = st[16*c + r + m];
          st[16*c + r]     = a.x*v0 - a.y*v1;
          st[16*c + r + m] = a.y*v0 + a.x*v1;
        }
      }
      { const float2 a5 = la[10];
#pragma unroll
        for (int j = 0; j < 16; ++j) {
          float v0 = st[16*c + j], v1 = t[j];
          st[16*c + j] = a5.x*v0 - a5.y*v1;
          t[j]         = a5.y*v0 + a5.x*v1;
        } }
#pragma unroll
      for (int p = 0; p < 8; ++p) Lf2[8*c + p] = make_float2(t[2*p], t[2*p+1]);
    }
    { const float2 a = la[11];   // bit4 RY (qubit 11), plain in-place
#pragma unroll
      for (int r = 0; r < 16; ++r) {
        float v0 = st[r], v1 = st[r + 16];
        st[r]      = a.x*v0 - a.y*v1;
        st[r + 16] = a.y*v0 + a.x*v1;
      }
#pragma unroll
      for (int p = 0; p < 8; ++p) {
        float2 A = Lf2[p], B = Lf2[p + 8];
        Lf2[p]     = make_float2(a.x*A.x - a.y*B.x, a.x*A.y - a.y*B.y);
        Lf2[p + 8] = make_float2(a.y*A.x + a.x*B.x, a.y*A.y + a.x*B.y);
      } }

    // ---- P2: lane-bit RYs (shfl on regs; partner-lane RMW on LDS) ----
    for (int e = 0; e < 6; ++e) {
      const float2 a = la[9 - e];
      const int m = LM[l][e];
      const float sg = (__popc(lane & LS[l][e]) & 1) ? a.y : -a.y;
#pragma unroll
      for (int r = 0; r < 32; ++r) {
        float o = __shfl_xor(st[r], m);
        st[r] = fmaf(sg, o, a.x * st[r]);
      }
      const float2* Pf2 = (const float2*)&Lbuf[wv][lane ^ m][0];
#pragma unroll
      for (int p = 0; p < 16; ++p) {
        float2 own = Lf2[p], oth = Pf2[p];
        Lf2[p] = make_float2(fmaf(sg, oth.x, a.x*own.x),
                             fmaf(sg, oth.y, a.x*own.y));
      }
    }

    // ---- P3: wave-bit RYs, 2 rounds (LDS half, then swapped reg half) ----
#pragma unroll
    for (int round = 0; round < 2; ++round) {
      for (int b = 0; b < 4; ++b) {
        __syncthreads();
        const float2 a = la[3 - b];
        const int m  = WM[l][b];
        const int pw = wv ^ m;
        const float sgS = (__popc(wv & WS[l][b]) & 1) ? a.y : -a.y;
        float2* P = (float2*)&Lbuf[pw][lane][0];
        const int pb = (wv < pw) ? 0 : 8;   // one-sided slot split
#pragma unroll
        for (int q = 0; q < 8; ++q) {
          float2 vS = Lf2[pb + q], vP = P[pb + q];
          Lf2[pb + q] = make_float2(a.x*vS.x + sgS*vP.x, a.x*vS.y + sgS*vP.y);
          P[pb + q]   = make_float2(a.x*vP.x - sgS*vS.x, a.x*vP.y - sgS*vS.y);
        }
      }
      __syncthreads();
      if (round == 0) {
        // SWAP1: plain st <-> L
#pragma unroll
        for (int p = 0; p < 16; ++p) {
          float2 r = Lf2[p];
          Lf2[p] = make_float2(st[2*p], st[2*p+1]);
          st[2*p] = r.x; st[2*p+1] = r.y;
        }
      } else {
        // SWAP2 + reg-cascade fold: L_new[q] = st_old[AQ[q]]; st gets L via
        // same slots, then rename CHI (CHI∘AQ = T5) -> canonical layout.
        float* Lrow = &Lbuf[wv][lane][0];
#pragma unroll
        for (int q = 0; q < 32; ++q) {
          float r = Lrow[q];
          Lrow[q] = st[AQ[q]];
          st[AQ[q]] = r;
        }
        float ns[32];
#pragma unroll
        for (int i = 0; i < 32; ++i) ns[CHI[i]] = st[i];
#pragma unroll
        for (int i = 0; i < 32; ++i) st[i] = ns[i];
      }
    }

    // ---- P4: CNOT boundary moves (same-wave only; no barriers needed) ----
    { const int tm = TM11[l];            // (12,11): ctrl waves, lane-target
      if (__popc(wv & WC[l]) & 1) {
#pragma unroll
        for (int r = 0; r < 32; ++r) st[r] = __shfl_xor(st[r], tm);
        const float2* Pf2 = (const float2*)&Lbuf[wv][lane ^ tm][0];
#pragma unroll
        for (int p = 0; p < 16; ++p) { float2 v = Pf2[p]; Lf2[p] = v; }
      } }
    { if (__popc(lane & LC[l]) & 1) {    // (6,5)' conjugated: st[k]<->L[k^31]
#pragma unroll
        for (int p = 0; p < 16; ++p) {
          float2 v = Lf2[p ^ 15];
          Lf2[p ^ 15] = make_float2(st[2*p+1], st[2*p]);
          st[2*p] = v.y; st[2*p+1] = v.x;
        }
      } }
  }

  // Output: lambda(0)=0 and canonical slots -> logical 0..15 = st[0..15]@tid0.
  if (tid == 0) {
#pragma unroll
    for (int j = 0; j < 16; ++j) out[batch * 16 + j] = st[j];
  }
}

extern "C" void kernel_launch(void* const* d_in, const int* in_sizes, int n_in,
                              void* d_out, int out_size, void* d_ws, size_t ws_size,
                              hipStream_t stream) {
  const float* x   = (const float*)d_in[0];
  const float* wts = (const float*)d_in[1];
  float* out = (float*)d_out;
  const int batch = in_sizes[0] / 16;   // 512
  qsim_kernel<<<dim3(batch), dim3(1024), 0, stream>>>(x, wts, out);
}